// Round 8
// baseline (166.758 us; speedup 1.0000x reference)
//
#include <hip/hip_runtime.h>
#include <hip/hip_bf16.h>

// LSTM cell, B=8192, IN=H=1024.
// R8: R4's schedule (lead-6 stage ring, vmcnt(4)@p4/p8) with RELAXED compiler
// fences: builtin s_barrier (no memory clobber) + bare lgkmcnt(0) asm, so the
// compiler may software-pipeline ds_reads/MFMAs across phase boundaries with
// its own counted lgkm waits (m201 template-faithful). vmcnt asms keep the
// clobber (compiler can't see the gload_lds -> ds_read dependency).

#define B_DIM 8192
#define H_DIM 1024
#define BH (8192 * 1024)
#define K2 2048

typedef __attribute__((ext_vector_type(4))) float f32x4;
typedef __attribute__((ext_vector_type(8))) __bf16 bf16x8;
typedef __attribute__((ext_vector_type(8))) unsigned short ushort8;

static __device__ __forceinline__ unsigned short f2bf(float f) {
    return __builtin_bit_cast(unsigned short, (__bf16)f);
}
static __device__ __forceinline__ float sigf(float x) {
    return 1.0f / (1.0f + __expf(-x));
}
static __device__ __forceinline__ float tanhft(float x) {
    float e = __expf(2.0f * x);
    return (e - 1.0f) / (e + 1.0f);
}
static __device__ __forceinline__ void gload16(const void* g, void* l) {
    __builtin_amdgcn_global_load_lds(
        (const __attribute__((address_space(1))) unsigned int*)g,
        (__attribute__((address_space(3))) unsigned int*)l, 16, 0, 0);
}
static __device__ __forceinline__ ushort8 cvt8(const float* src) {
    const float4 u = ((const float4*)src)[0];
    const float4 v = ((const float4*)src)[1];
    ushort8 o;
    o[0] = f2bf(u.x); o[1] = f2bf(u.y); o[2] = f2bf(u.z); o[3] = f2bf(u.w);
    o[4] = f2bf(v.x); o[5] = f2bf(v.y); o[6] = f2bf(v.z); o[7] = f2bf(v.w);
    return o;
}

// ---- merged conversion kernel ----
__global__ __launch_bounds__(256) void conv_kernel(
    const float* __restrict__ x, const float* __restrict__ h,
    const float* __restrict__ Wx, const float* __restrict__ Wh,
    unsigned short* __restrict__ A, unsigned short* __restrict__ W)
{
    const int bidx = blockIdx.x;
    if (bidx < 8192) {
        const int id = bidx * 256 + threadIdx.x;
        const int base = id * 8;
        const int b = base >> 11;
        const int k = base & 2047;
        const float* src = (k < 1024) ? (x + (size_t)b * 1024 + k)
                                      : (h + (size_t)b * 1024 + (k - 1024));
        *(ushort8*)(A + base) = cvt8(src);
    } else {
        const int id = (bidx - 8192) * 256 + threadIdx.x;
        const int base = id * 8;
        const int n = base >> 11;
        const int k = base & 2047;
        const int jb = n >> 8, wn = (n >> 6) & 3, g = (n >> 4) & 3, jj = n & 15;
        const int srow = (g << 10) + (jb << 6) + (wn << 4) + jj;
        const float* src = (k < 1024) ? (Wx + (size_t)srow * 1024 + k)
                                      : (Wh + (size_t)srow * 1024 + (k - 1024));
        *(ushort8*)(W + base) = cvt8(src);
    }
}

// ==================== 256x256 8-phase GEMM ====================
// LDS (128 KiB, ushort offsets): [buf<<15] | [isB<<14] | [ks<<13] | row*32 | chunk*8
// chunk swizzle: physical chunk = logical_k8 ^ ((row>>1)&3)
__global__ __launch_bounds__(512, 2) void lstm_gemm8(
    const unsigned short* __restrict__ Abf, const unsigned short* __restrict__ Wbf,
    const float* __restrict__ bx, const float* __restrict__ bh,
    const float* __restrict__ cprev, float* __restrict__ out)
{
    extern __shared__ unsigned short lds[];

    const int tid = threadIdx.x;
    const int lane = tid & 63;
    const int wv = tid >> 6;
    const int wm = wv >> 2;          // 0..1
    const int wn = wv & 3;           // 0..3
    const int q = lane >> 4, c = lane & 15;

    // XCD-local jb-pair ordering (neutral but harmless)
    const int bid = blockIdx.x;      // 0..511
    const int xcd = bid & 7;
    const int idx = bid >> 3;        // 0..63
    const int jb  = xcd * 2 + (idx & 1);   // 0..15
    const int bb  = idx >> 1;              // 0..31
    const int b0 = bb * 256;

    const unsigned short* Ab = Abf + (size_t)b0 * K2;
    const unsigned short* Wb = Wbf + (size_t)(jb * 256) * K2;

    // staging: chunk ci -> row=ci>>2; pre-swizzled global k8 = (ci&3) ^ ((row>>1)&3)
    const int srow = tid >> 2;
    const int sk8g = (tid & 3) ^ ((tid >> 3) & 3);
    const size_t ss0 = (size_t)srow * K2 + (size_t)sk8g * 8;
    const unsigned sdst = (unsigned)(tid & 448) * 8;  // wave-uniform chunk base

    // fragment reads: physical chunk = q ^ ((row>>1)&3); (row>>1)&3 == (c>>1)&3
    const int cq = ((q ^ ((c >> 1) & 3)) << 3);
    const unsigned aoff = (unsigned)(wm * 128 + c) * 32 + cq;
    const unsigned boff = 16384u + (unsigned)(wn * 64 + c) * 32 + cq;

    f32x4 acc[8][4];
#pragma unroll
    for (int m = 0; m < 8; ++m)
#pragma unroll
        for (int g = 0; g < 4; ++g) acc[m][g] = f32x4{0.f, 0.f, 0.f, 0.f};

    bf16x8 av[4], bv[4];

#define STAGE(TP, T, ISB, KS) do {                                             \
    const unsigned short* _s = (ISB) ? Wb : Ab;                                \
    const size_t _o = ss0 + (size_t)((T) & 31) * 64 + (KS) * 32;               \
    const unsigned _d = ((TP) << 15) | ((ISB) << 14) | ((KS) << 13);           \
    gload16(_s + _o, &lds[_d + sdst]);                                         \
    gload16(_s + (size_t)128 * K2 + _o, &lds[_d + 4096u + sdst]);              \
} while (0)

#define LOADA(BUF, KS, MH) do {                                                \
    const unsigned short* _p = lds + (BUF) * 32768 + (KS) * 8192 + aoff + (MH) * 2048; \
    av[0] = *(const bf16x8*)(_p);                                              \
    av[1] = *(const bf16x8*)(_p + 512);                                        \
    av[2] = *(const bf16x8*)(_p + 1024);                                       \
    av[3] = *(const bf16x8*)(_p + 1536);                                       \
} while (0)

#define LOADB(BUF, KS) do {                                                    \
    const unsigned short* _p = lds + (BUF) * 32768 + (KS) * 8192 + boff;       \
    bv[0] = *(const bf16x8*)(_p);                                              \
    bv[1] = *(const bf16x8*)(_p + 512);                                        \
    bv[2] = *(const bf16x8*)(_p + 1024);                                       \
    bv[3] = *(const bf16x8*)(_p + 1536);                                       \
} while (0)

#define MFMA16(MH) do {                                                        \
    __builtin_amdgcn_s_setprio(1);                                             \
    _Pragma("unroll")                                                          \
    for (int _i = 0; _i < 4; ++_i)                                             \
        _Pragma("unroll")                                                      \
        for (int _g = 0; _g < 4; ++_g)                                         \
            acc[(MH) * 4 + _i][_g] = __builtin_amdgcn_mfma_f32_16x16x32_bf16(  \
                av[_i], bv[_g], acc[(MH) * 4 + _i][_g], 0, 0, 0);              \
    __builtin_amdgcn_s_setprio(0);                                             \
} while (0)

#define BAR()    __builtin_amdgcn_s_barrier()
#define WLGKM0() asm volatile("s_waitcnt lgkmcnt(0)")
#define WVM4()   asm volatile("s_waitcnt vmcnt(4)" ::: "memory")

#define PH(BUF, KS, MH, RB, STP, ST, SB, SK) do {                              \
    LOADA(BUF, KS, MH);                                                        \
    if (RB) LOADB(BUF, KS);                                                    \
    STAGE(STP, ST, SB, SK);                                                    \
    BAR();                                                                     \
    WLGKM0();                                                                  \
    MFMA16(MH);                                                                \
    BAR();                                                                     \
} while (0)

#define PHV(BUF, KS, MH, STP, ST, SB, SK) do {                                 \
    LOADA(BUF, KS, MH);                                                        \
    STAGE(STP, ST, SB, SK);                                                    \
    BAR();                                                                     \
    WLGKM0();                                                                  \
    MFMA16(MH);                                                                \
    WVM4();                                                                    \
    BAR();                                                                     \
} while (0)

    // prologue: buf0{ks0A,ks0B,ks1A,ks1B}, buf1{ks0A,ks0B} = 12 vmem instrs
    STAGE(0, 0, 0, 0); STAGE(0, 0, 1, 0); STAGE(0, 0, 0, 1); STAGE(0, 0, 1, 1);
    STAGE(1, 1, 0, 0); STAGE(1, 1, 1, 0);
    WVM4();            // retire buf0.ks0 + buf0.ks1; buf1.ks0 stays in flight
    BAR();

    // steady state: stage lead-6; vmcnt(4) at phases 4 & 8 retires 2 regions.
    for (int u = 0; u < 32; u += 2) {
        PH (0, 0, 0, 1, 1, u + 1, 0, 1);   // p1: stage buf1.A.ks1(u+1)
        PH (0, 0, 1, 0, 1, u + 1, 1, 1);   // p2: stage buf1.B.ks1(u+1)
        PH (0, 1, 0, 1, 0, u + 2, 0, 0);   // p3: stage buf0.A.ks0(u+2)
        PHV(0, 1, 1,    0, u + 2, 1, 0);   // p4: vm -> buf1.ks0, buf1.ks1 ready
        PH (1, 0, 0, 1, 0, u + 2, 0, 1);   // p5: stage buf0.A.ks1(u+2)
        PH (1, 0, 1, 0, 0, u + 2, 1, 1);   // p6: stage buf0.B.ks1(u+2)
        PH (1, 1, 0, 1, 1, u + 3, 0, 0);   // p7: stage buf1.A.ks0(u+3)
        PHV(1, 1, 1,    1, u + 3, 1, 0);   // p8: vm -> buf0.ks0, buf0.ks1 ready
    }

#undef PH
#undef PHV
#undef STAGE
#undef LOADA
#undef LOADB
#undef MFMA16

    // ---- fused LSTM epilogue (C/D: col=lane&15, row=(lane>>4)*4+rr) ----
    const int j = jb * 64 + wn * 16 + c;
    const float bI = bx[j] + bh[j];
    const float bF = bx[1024 + j] + bh[1024 + j];
    const float bG = bx[2048 + j] + bh[2048 + j];
    const float bO = bx[3072 + j] + bh[3072 + j];
#pragma unroll
    for (int mt = 0; mt < 8; ++mt) {
#pragma unroll
        for (int rr = 0; rr < 4; ++rr) {
            const int row = b0 + wm * 128 + mt * 16 + q * 4 + rr;
            const size_t off = (size_t)row * 1024 + j;
            const float iv = sigf(acc[mt][0][rr] + bI);
            const float fv = sigf(acc[mt][1][rr] + bF);
            const float gv = tanhft(acc[mt][2][rr] + bG);
            const float ov = sigf(acc[mt][3][rr] + bO);
            const float cp = cprev[off];
            const float nc = fv * cp + iv * gv;
            out[off] = ov * tanhft(nc);   // new_h
            out[BH + off] = nc;           // new_c
        }
    }
}

// ================== fallback (R2 128^2 kernel) if ws too small ==================
__global__ __launch_bounds__(256) void lstm_fallback(
    const float* __restrict__ incoming, const float* __restrict__ state,
    const float* __restrict__ Wx, const float* __restrict__ bx,
    const float* __restrict__ Wh, const float* __restrict__ bh,
    float* __restrict__ out)
{
    __shared__ unsigned short lA[128 * 64];
    __shared__ unsigned short lW[128 * 64];
    const int t = threadIdx.x;
    const int lane = t & 63;
    const int wv = t >> 6;
    const int q = lane >> 4;
    const int c = lane & 15;
    const int j0 = blockIdx.x * 32;
    const int b0 = blockIdx.y * 128;
    const float* hprev = state;
    const float* cprev = state + (size_t)BH;

    f32x4 acc[2][8];
#pragma unroll
    for (int mt = 0; mt < 2; ++mt)
#pragma unroll
        for (int nt = 0; nt < 8; ++nt)
            acc[mt][nt] = f32x4{0.f, 0.f, 0.f, 0.f};

    const int sr = t >> 3;
    const int sk8 = t & 7;

    for (int it = 0; it < 32; ++it) {
        const bool first = (it < 16);
        const float* As = first ? incoming : hprev;
        const float* Ws = first ? Wx : Wh;
        const int kk = first ? it * 64 : it * 64 - 1024;
#pragma unroll
        for (int i = 0; i < 4; ++i) {
            const int r = i * 32 + sr;
            *(ushort8*)&lA[r * 64 + ((sk8 ^ (r & 7)) * 8)] =
                cvt8(As + (size_t)(b0 + r) * 1024 + kk + sk8 * 8);
        }
#pragma unroll
        for (int i = 0; i < 4; ++i) {
            const int n = i * 32 + sr;
            const int grow = ((n >> 5) << 10) + j0 + (n & 31);
            *(ushort8*)&lW[n * 64 + ((sk8 ^ (n & 7)) * 8)] =
                cvt8(Ws + (size_t)grow * 1024 + kk + sk8 * 8);
        }
        __syncthreads();
#pragma unroll
        for (int ks = 0; ks < 2; ++ks) {
            const int k8a = ks * 4 + q;
            bf16x8 av[2], bv[8];
#pragma unroll
            for (int mt = 0; mt < 2; ++mt) {
                const int r = wv * 32 + mt * 16 + c;
                av[mt] = *(const bf16x8*)&lA[r * 64 + ((k8a ^ (r & 7)) * 8)];
            }
#pragma unroll
            for (int nt = 0; nt < 8; ++nt) {
                const int n = nt * 16 + c;
                bv[nt] = *(const bf16x8*)&lW[n * 64 + ((k8a ^ (n & 7)) * 8)];
            }
#pragma unroll
            for (int mt = 0; mt < 2; ++mt)
#pragma unroll
                for (int nt = 0; nt < 8; ++nt)
                    acc[mt][nt] = __builtin_amdgcn_mfma_f32_16x16x32_bf16(
                        av[mt], bv[nt], acc[mt][nt], 0, 0, 0);
        }
        __syncthreads();
    }

    const int b0r = b0 + wv * 32;
#pragma unroll
    for (int jt = 0; jt < 2; ++jt) {
        const int j = j0 + jt * 16 + c;
        const float bI = bx[j] + bh[j];
        const float bF = bx[1024 + j] + bh[1024 + j];
        const float bG = bx[2048 + j] + bh[2048 + j];
        const float bO = bx[3072 + j] + bh[3072 + j];
#pragma unroll
        for (int mt = 0; mt < 2; ++mt) {
#pragma unroll
            for (int rr = 0; rr < 4; ++rr) {
                const int row = b0r + mt * 16 + q * 4 + rr;
                const size_t off = (size_t)row * 1024 + j;
                const float iv = sigf(acc[mt][0 + jt][rr] + bI);
                const float fv = sigf(acc[mt][2 + jt][rr] + bF);
                const float gv = tanhft(acc[mt][4 + jt][rr] + bG);
                const float ov = sigf(acc[mt][6 + jt][rr] + bO);
                const float cp = cprev[off];
                const float nc = fv * cp + iv * gv;
                out[off] = ov * tanhft(nc);
                out[BH + off] = nc;
            }
        }
    }
}

extern "C" void kernel_launch(void* const* d_in, const int* in_sizes, int n_in,
                              void* d_out, int out_size, void* d_ws, size_t ws_size,
                              hipStream_t stream) {
    const float* incoming = (const float*)d_in[0];
    const float* state    = (const float*)d_in[1];
    const float* Wx       = (const float*)d_in[2];
    const float* bx       = (const float*)d_in[3];
    const float* Wh       = (const float*)d_in[4];
    const float* bh       = (const float*)d_in[5];
    float* out = (float*)d_out;

    const float* hprev = state;
    const float* cprev = state + (size_t)BH;

    const size_t A_bytes = (size_t)B_DIM * K2 * 2;       // 32 MiB
    const size_t W_bytes = (size_t)4 * H_DIM * K2 * 2;   // 16 MiB

    if (ws_size >= A_bytes + W_bytes) {
        unsigned short* Abf = (unsigned short*)d_ws;
        unsigned short* Wbf = (unsigned short*)((char*)d_ws + A_bytes);
        conv_kernel<<<dim3(12288), dim3(256), 0, stream>>>(
            incoming, hprev, Wx, Wh, Abf, Wbf);
        (void)hipFuncSetAttribute((const void*)lstm_gemm8,
                                  hipFuncAttributeMaxDynamicSharedMemorySize, 131072);
        lstm_gemm8<<<dim3(512), dim3(512), 131072, stream>>>(
            Abf, Wbf, bx, bh, cprev, out);
    } else {
        dim3 grid(H_DIM / 32, B_DIM / 128);
        lstm_fallback<<<grid, dim3(256), 0, stream>>>(
            incoming, state, Wx, bx, Wh, bh, out);
    }
}

// Round 9
// 159.003 us; speedup vs baseline: 1.0488x; 1.0488x over previous
//
#include <hip/hip_runtime.h>
#include <hip/hip_bf16.h>

// LSTM cell, B=8192, IN=H=1024.
// R9: m201-geometry LDS regions — {buf}x{A,B} of [256 rows][64 k] with 128-B
// rows, per-row XOR swizzle (chunk = k8 ^ (row&7)); stage = 64-row quarters,
// each gload fully 128B-line-coalesced (8 lanes = 1 line). Counted vmcnt(2)
// at p1/p4. Schedule otherwise as R8 (relaxed fences, setprio, XCD jb-pairs).

#define B_DIM 8192
#define H_DIM 1024
#define BH (8192 * 1024)
#define K2 2048

typedef __attribute__((ext_vector_type(4))) float f32x4;
typedef __attribute__((ext_vector_type(8))) __bf16 bf16x8;
typedef __attribute__((ext_vector_type(8))) unsigned short ushort8;

static __device__ __forceinline__ unsigned short f2bf(float f) {
    return __builtin_bit_cast(unsigned short, (__bf16)f);
}
static __device__ __forceinline__ float sigf(float x) {
    return 1.0f / (1.0f + __expf(-x));
}
static __device__ __forceinline__ float tanhft(float x) {
    float e = __expf(2.0f * x);
    return (e - 1.0f) / (e + 1.0f);
}
static __device__ __forceinline__ void gload16(const void* g, void* l) {
    __builtin_amdgcn_global_load_lds(
        (const __attribute__((address_space(1))) unsigned int*)g,
        (__attribute__((address_space(3))) unsigned int*)l, 16, 0, 0);
}
static __device__ __forceinline__ ushort8 cvt8(const float* src) {
    const float4 u = ((const float4*)src)[0];
    const float4 v = ((const float4*)src)[1];
    ushort8 o;
    o[0] = f2bf(u.x); o[1] = f2bf(u.y); o[2] = f2bf(u.z); o[3] = f2bf(u.w);
    o[4] = f2bf(v.x); o[5] = f2bf(v.y); o[6] = f2bf(v.z); o[7] = f2bf(v.w);
    return o;
}

// ---- merged conversion kernel (unchanged) ----
__global__ __launch_bounds__(256) void conv_kernel(
    const float* __restrict__ x, const float* __restrict__ h,
    const float* __restrict__ Wx, const float* __restrict__ Wh,
    unsigned short* __restrict__ A, unsigned short* __restrict__ W)
{
    const int bidx = blockIdx.x;
    if (bidx < 8192) {
        const int id = bidx * 256 + threadIdx.x;
        const int base = id * 8;
        const int b = base >> 11;
        const int k = base & 2047;
        const float* src = (k < 1024) ? (x + (size_t)b * 1024 + k)
                                      : (h + (size_t)b * 1024 + (k - 1024));
        *(ushort8*)(A + base) = cvt8(src);
    } else {
        const int id = (bidx - 8192) * 256 + threadIdx.x;
        const int base = id * 8;
        const int n = base >> 11;
        const int k = base & 2047;
        const int jb = n >> 8, wn = (n >> 6) & 3, g = (n >> 4) & 3, jj = n & 15;
        const int srow = (g << 10) + (jb << 6) + (wn << 4) + jj;
        const float* src = (k < 1024) ? (Wx + (size_t)srow * 1024 + k)
                                      : (Wh + (size_t)srow * 1024 + (k - 1024));
        *(ushort8*)(W + base) = cvt8(src);
    }
}

// ==================== 256x256 8-phase GEMM, 128B-row LDS ====================
// LDS (128 KiB, ushort units): region(buf, isB) = buf*32768 + isB*16384;
// element (row r in [0,256), k in [0,64)): r*64 + ((k>>3 ^ (r&7))<<3) + (k&7).
// Stage quarter QA: thread tid writes global (row = QA*64 + tid>>3,
// k8 = (tid&7)^((tid>>3)&7)) -> lds chunk QA*4096 + tid*8 (linear dest,
// inverse-swizzled source; 8 lanes = one full 128B global line).
__global__ __launch_bounds__(512, 2) void lstm_gemm8(
    const unsigned short* __restrict__ Abf, const unsigned short* __restrict__ Wbf,
    const float* __restrict__ bx, const float* __restrict__ bh,
    const float* __restrict__ cprev, float* __restrict__ out)
{
    extern __shared__ unsigned short lds[];

    const int tid = threadIdx.x;
    const int lane = tid & 63;
    const int wv = tid >> 6;
    const int wm = wv >> 2;          // 0..1
    const int wn = wv & 3;           // 0..3
    const int q = lane >> 4, c = lane & 15;

    // XCD-local jb-pair ordering
    const int bid = blockIdx.x;      // 0..511
    const int xcd = bid & 7;
    const int idx = bid >> 3;        // 0..63
    const int jb  = xcd * 2 + (idx & 1);   // 0..15
    const int bb  = idx >> 1;              // 0..31
    const int b0 = bb * 256;

    const unsigned short* Ab = Abf + (size_t)b0 * K2;
    const unsigned short* Wb = Wbf + (size_t)(jb * 256) * K2;

    // staging: thread covers row = QA*64 + (tid>>3), global chunk pre-swizzled
    const size_t ssg = (size_t)(tid >> 3) * K2
                     + (size_t)(((tid & 7) ^ ((tid >> 3) & 7)) * 8);
    const unsigned sbase = (unsigned)(tid & 448) * 8;  // wave-uniform dest base

    // fragment read bases: row&7 == c&7 for all fragment rows (16-multiples + c)
    const unsigned arow = (unsigned)(wm * 128 + c) * 64;
    const unsigned brow = 16384u + (unsigned)(wn * 64 + c) * 64;
    const unsigned cach = (unsigned)((q ^ (c & 7)) << 3);

    f32x4 acc[8][4];
#pragma unroll
    for (int m = 0; m < 8; ++m)
#pragma unroll
        for (int g = 0; g < 4; ++g) acc[m][g] = f32x4{0.f, 0.f, 0.f, 0.f};

    bf16x8 av[4], bv[4];

// one gload: quarter QA of region (BUF, ISB), tile T
#define STG(BUF, ISB, QA, T) do {                                              \
    const unsigned short* _s = (ISB) ? Wb : Ab;                                \
    gload16(_s + ssg + (size_t)(QA) * 64 * K2 + (size_t)((T) & 31) * 64,       \
            &lds[(BUF) * 32768 + (ISB) * 16384 + (QA) * 4096 + sbase]);        \
} while (0)

#define LOADA(BUF, KS, MH) do {                                                \
    const unsigned short* _p = lds + (BUF) * 32768 + (MH) * 4096 + arow        \
                             + (cach ^ ((KS) * 32));                           \
    av[0] = *(const bf16x8*)(_p);                                              \
    av[1] = *(const bf16x8*)(_p + 1024);                                       \
    av[2] = *(const bf16x8*)(_p + 2048);                                       \
    av[3] = *(const bf16x8*)(_p + 3072);                                       \
} while (0)

#define LOADB(BUF, KS) do {                                                    \
    const unsigned short* _p = lds + (BUF) * 32768 + brow                      \
                             + (cach ^ ((KS) * 32));                           \
    bv[0] = *(const bf16x8*)(_p);                                              \
    bv[1] = *(const bf16x8*)(_p + 1024);                                       \
    bv[2] = *(const bf16x8*)(_p + 2048);                                       \
    bv[3] = *(const bf16x8*)(_p + 3072);                                       \
} while (0)

#define MFMA16(MH) do {                                                        \
    __builtin_amdgcn_s_setprio(1);                                             \
    _Pragma("unroll")                                                          \
    for (int _i = 0; _i < 4; ++_i)                                             \
        _Pragma("unroll")                                                      \
        for (int _g = 0; _g < 4; ++_g)                                         \
            acc[(MH) * 4 + _i][_g] = __builtin_amdgcn_mfma_f32_16x16x32_bf16(  \
                av[_i], bv[_g], acc[(MH) * 4 + _i][_g], 0, 0, 0);              \
    __builtin_amdgcn_s_setprio(0);                                             \
} while (0)

#define BAR()    __builtin_amdgcn_s_barrier()
#define WLGKM0() asm volatile("s_waitcnt lgkmcnt(0)")
#define WVM2()   asm volatile("s_waitcnt vmcnt(2)" ::: "memory")

// 4 phases per K-tile (tile T in BUF, staging tile T+1 into BUF^1):
// p1: ks0/mh0 + B(ks0); stage B-q0,q1; vmcnt(2) retires prev A-q1,q3
// p2: ks0/mh1;          stage B-q2,q3
// p3: ks1/mh0 + B(ks1); stage A-q0,q2
// p4: ks1/mh1;          stage A-q1,q3; vmcnt(2) retires B-all + A-q0,q2
#define TILE(BUF, T1) do {                                                     \
    LOADA(BUF, 0, 0); LOADB(BUF, 0);                                           \
    STG((BUF) ^ 1, 1, 0, T1); STG((BUF) ^ 1, 1, 1, T1);                        \
    BAR(); WLGKM0(); MFMA16(0); WVM2(); BAR();                                 \
    LOADA(BUF, 0, 1);                                                          \
    STG((BUF) ^ 1, 1, 2, T1); STG((BUF) ^ 1, 1, 3, T1);                        \
    BAR(); WLGKM0(); MFMA16(1); BAR();                                         \
    LOADA(BUF, 1, 0); LOADB(BUF, 1);                                           \
    STG((BUF) ^ 1, 0, 0, T1); STG((BUF) ^ 1, 0, 2, T1);                        \
    BAR(); WLGKM0(); MFMA16(0); BAR();                                         \
    LOADA(BUF, 1, 1);                                                          \
    STG((BUF) ^ 1, 0, 1, T1); STG((BUF) ^ 1, 0, 3, T1);                        \
    BAR(); WLGKM0(); MFMA16(1); WVM2(); BAR();                                 \
} while (0)

    // prologue: tile0 -> buf0: B q0-q3, A q0,q2,q1,q3 (8 gloads);
    // vmcnt(2) retires B + A-q0,q2 (leaves A-q1,q3 = steady-state carry-in)
    STG(0, 1, 0, 0); STG(0, 1, 1, 0); STG(0, 1, 2, 0); STG(0, 1, 3, 0);
    STG(0, 0, 0, 0); STG(0, 0, 2, 0); STG(0, 0, 1, 0); STG(0, 0, 3, 0);
    WVM2();
    BAR();

    for (int u = 0; u < 32; u += 2) {
        TILE(0, u + 1);   // tile u   (buf0), stage u+1 -> buf1
        TILE(1, u + 2);   // tile u+1 (buf1), stage u+2 -> buf0 (u=30: wraps, benign)
    }

#undef TILE
#undef STG
#undef LOADA
#undef LOADB
#undef MFMA16

    // ---- fused LSTM epilogue (C/D: col=lane&15, row=(lane>>4)*4+rr) ----
    const int j = jb * 64 + wn * 16 + c;
    const float bI = bx[j] + bh[j];
    const float bF = bx[1024 + j] + bh[1024 + j];
    const float bG = bx[2048 + j] + bh[2048 + j];
    const float bO = bx[3072 + j] + bh[3072 + j];
#pragma unroll
    for (int mt = 0; mt < 8; ++mt) {
#pragma unroll
        for (int rr = 0; rr < 4; ++rr) {
            const int row = b0 + wm * 128 + mt * 16 + q * 4 + rr;
            const size_t off = (size_t)row * 1024 + j;
            const float iv = sigf(acc[mt][0][rr] + bI);
            const float fv = sigf(acc[mt][1][rr] + bF);
            const float gv = tanhft(acc[mt][2][rr] + bG);
            const float ov = sigf(acc[mt][3][rr] + bO);
            const float cp = cprev[off];
            const float nc = fv * cp + iv * gv;
            out[off] = ov * tanhft(nc);   // new_h
            out[BH + off] = nc;           // new_c
        }
    }
}

// ================== fallback (R2 128^2 kernel) if ws too small ==================
__global__ __launch_bounds__(256) void lstm_fallback(
    const float* __restrict__ incoming, const float* __restrict__ state,
    const float* __restrict__ Wx, const float* __restrict__ bx,
    const float* __restrict__ Wh, const float* __restrict__ bh,
    float* __restrict__ out)
{
    __shared__ unsigned short lA[128 * 64];
    __shared__ unsigned short lW[128 * 64];
    const int t = threadIdx.x;
    const int lane = t & 63;
    const int wv = t >> 6;
    const int q = lane >> 4;
    const int c = lane & 15;
    const int j0 = blockIdx.x * 32;
    const int b0 = blockIdx.y * 128;
    const float* hprev = state;
    const float* cprev = state + (size_t)BH;

    f32x4 acc[2][8];
#pragma unroll
    for (int mt = 0; mt < 2; ++mt)
#pragma unroll
        for (int nt = 0; nt < 8; ++nt)
            acc[mt][nt] = f32x4{0.f, 0.f, 0.f, 0.f};

    const int sr = t >> 3;
    const int sk8 = t & 7;

    for (int it = 0; it < 32; ++it) {
        const bool first = (it < 16);
        const float* As = first ? incoming : hprev;
        const float* Ws = first ? Wx : Wh;
        const int kk = first ? it * 64 : it * 64 - 1024;
#pragma unroll
        for (int i = 0; i < 4; ++i) {
            const int r = i * 32 + sr;
            *(ushort8*)&lA[r * 64 + ((sk8 ^ (r & 7)) * 8)] =
                cvt8(As + (size_t)(b0 + r) * 1024 + kk + sk8 * 8);
        }
#pragma unroll
        for (int i = 0; i < 4; ++i) {
            const int n = i * 32 + sr;
            const int grow = ((n >> 5) << 10) + j0 + (n & 31);
            *(ushort8*)&lW[n * 64 + ((sk8 ^ (n & 7)) * 8)] =
                cvt8(Ws + (size_t)grow * 1024 + kk + sk8 * 8);
        }
        __syncthreads();
#pragma unroll
        for (int ks = 0; ks < 2; ++ks) {
            const int k8a = ks * 4 + q;
            bf16x8 av[2], bv[8];
#pragma unroll
            for (int mt = 0; mt < 2; ++mt) {
                const int r = wv * 32 + mt * 16 + c;
                av[mt] = *(const bf16x8*)&lA[r * 64 + ((k8a ^ (r & 7)) * 8)];
            }
#pragma unroll
            for (int nt = 0; nt < 8; ++nt) {
                const int n = nt * 16 + c;
                bv[nt] = *(const bf16x8*)&lW[n * 64 + ((k8a ^ (n & 7)) * 8)];
            }
#pragma unroll
            for (int mt = 0; mt < 2; ++mt)
#pragma unroll
                for (int nt = 0; nt < 8; ++nt)
                    acc[mt][nt] = __builtin_amdgcn_mfma_f32_16x16x32_bf16(
                        av[mt], bv[nt], acc[mt][nt], 0, 0, 0);
        }
        __syncthreads();
    }

    const int b0r = b0 + wv * 32;
#pragma unroll
    for (int jt = 0; jt < 2; ++jt) {
        const int j = j0 + jt * 16 + c;
        const float bI = bx[j] + bh[j];
        const float bF = bx[1024 + j] + bh[1024 + j];
        const float bG = bx[2048 + j] + bh[2048 + j];
        const float bO = bx[3072 + j] + bh[3072 + j];
#pragma unroll
        for (int mt = 0; mt < 2; ++mt) {
#pragma unroll
            for (int rr = 0; rr < 4; ++rr) {
                const int row = b0r + mt * 16 + q * 4 + rr;
                const size_t off = (size_t)row * 1024 + j;
                const float iv = sigf(acc[mt][0 + jt][rr] + bI);
                const float fv = sigf(acc[mt][2 + jt][rr] + bF);
                const float gv = tanhft(acc[mt][4 + jt][rr] + bG);
                const float ov = sigf(acc[mt][6 + jt][rr] + bO);
                const float cp = cprev[off];
                const float nc = fv * cp + iv * gv;
                out[off] = ov * tanhft(nc);
                out[BH + off] = nc;
            }
        }
    }
}

extern "C" void kernel_launch(void* const* d_in, const int* in_sizes, int n_in,
                              void* d_out, int out_size, void* d_ws, size_t ws_size,
                              hipStream_t stream) {
    const float* incoming = (const float*)d_in[0];
    const float* state    = (const float*)d_in[1];
    const float* Wx       = (const float*)d_in[2];
    const float* bx       = (const float*)d_in[3];
    const float* Wh       = (const float*)d_in[4];
    const float* bh       = (const float*)d_in[5];
    float* out = (float*)d_out;

    const float* hprev = state;
    const float* cprev = state + (size_t)BH;

    const size_t A_bytes = (size_t)B_DIM * K2 * 2;       // 32 MiB
    const size_t W_bytes = (size_t)4 * H_DIM * K2 * 2;   // 16 MiB

    if (ws_size >= A_bytes + W_bytes) {
        unsigned short* Abf = (unsigned short*)d_ws;
        unsigned short* Wbf = (unsigned short*)((char*)d_ws + A_bytes);
        conv_kernel<<<dim3(12288), dim3(256), 0, stream>>>(
            incoming, hprev, Wx, Wh, Abf, Wbf);
        (void)hipFuncSetAttribute((const void*)lstm_gemm8,
                                  hipFuncAttributeMaxDynamicSharedMemorySize, 131072);
        lstm_gemm8<<<dim3(512), dim3(512), 131072, stream>>>(
            Abf, Wbf, bx, bh, cprev, out);
    } else {
        dim3 grid(H_DIM / 32, B_DIM / 128);
        lstm_fallback<<<grid, dim3(256), 0, stream>>>(
            incoming, state, Wx, bx, Wh, bh, out);
    }
}